// Round 17
// baseline (230.714 us; speedup 1.0000x reference)
//
#include <hip/hip_runtime.h>
#include <hip/hip_bf16.h>
#include <stdint.h>

#define BB 32
#define GG 100
#define AA 8400
#define TPB 256
#define NCH 33                         // ceil(8400/256) chunks per image
#define BA (BB*AA)
#define NG (BB*GG)
#define NB2 (BB*GG)                    // kM/kR blocks / partial count
#define GCAP 128                       // geo cap (provably <= 75 per gt)
#define SCAP (GG*10)                   // selection slots per image (g*10+k)
#define NT10 (NCH*10)                  // 330 top-10 partials per (b,g)

typedef __hip_bfloat16 bf16;

struct P {
  const void *outs, *labs, *ss;
  float4 *box4, *gtb, *gtc;           // per-anchor box; per-gt box/center
  float2 *aux2;                       // per-anchor (fg? area : -area, cpk bits)
  float *pcc, *zl;                    // per-anchor cls-cost / cls logit
  float *top10;                       // [NB2][NCH][10] per-chunk top-10 ious
  float *gcostL;                      // [NB2][GCAP] geo costs
  int   *gposL;                       // [NB2][GCAP] geo anchor ids
  int   *gct;                         // [NB2] geo counts
  int   *sel_a;                       // [BB][SCAP] selected anchor id, -1 empty
  float *sel_iou;                     // [BB][SCAP] its iou
  int   *cnt, *own;                   // per-anchor selection count / min slot
  float *pb, *pf;                     // per-(b,g) BCE / fg partials
  int *gmax;
  float *out;
};

// runtime input-dtype detection: strides[0]==8.0
// f32 word 0x41000000 ; bf16 pair (8.0,8.0) 0x41004100
__device__ __forceinline__ int dtypeFlag(const void* ss){
  return (((const uint32_t*)ss)[0] == 0x41000000u) ? 1 : 0;
}
__device__ __forceinline__ float ld(const void* p, int i, int isf32){
  return isf32 ? ((const float*)p)[i] : __bfloat162float(((const bf16*)p)[i]);
}
// analytic anchor geometry (exact: ints + pow2 strides exact in f32/bf16)
__device__ __forceinline__ void ageom(int a, float& xc, float& yc, float& r){
  int x, y, s;
  if (a < 6400){ x = a % 80; y = a / 80; s = 8; }
  else if (a < 8000){ int q = a - 6400; x = q % 40; y = q / 40; s = 16; }
  else { int q = a - 8000; x = q % 20; y = q / 20; s = 32; }
  float fs = (float)s;
  xc = ((float)x + 0.5f) * fs;
  yc = ((float)y + 0.5f) * fs;
  r  = 2.5f * fs;
}
// pack integer center + level: xc(10) | yc(10)<<10 | lvl<<20
__device__ __forceinline__ uint32_t apack2(int a){
  int x, y, s, lvl;
  if (a < 6400){ x = a % 80; y = a / 80; s = 8; lvl = 0; }
  else if (a < 8000){ int q = a - 6400; x = q % 40; y = q / 40; s = 16; lvl = 1; }
  else { int q = a - 8000; x = q % 20; y = q / 20; s = 32; lvl = 2; }
  return (uint32_t)(x*s + s/2) | ((uint32_t)(y*s + s/2) << 10) | ((uint32_t)lvl << 20);
}

// ---- kA: gt structs + per-anchor staging + fg (r14 verbatim + gct init) ---
__global__ __launch_bounds__(TPB) void kA(P p){
  __shared__ float4 s_gtb[GG], s_gtc[GG];
  __shared__ float s_o[TPB*6];
  __shared__ int s_ng;
  int t = threadIdx.x;
  int c = blockIdx.x, b = blockIdx.y;
  int isf = dtypeFlag(p.ss);
  if (t == 0) s_ng = 0;
  {
    int s = c*TPB + t;
    if (s < SCAP) p.sel_a[b*SCAP + s] = -1;        // empty slot marker
    if (s < GG)   p.gct[b*GG + s] = 0;             // geo list counter
  }
  int nel = min(TPB*6, AA*6 - c*(TPB*6));      // floats in this chunk
  if (isf){
    const float4* src = (const float4*)((const float*)p.outs + (size_t)b*AA*6 + (size_t)c*(TPB*6));
    float4* dst = (float4*)s_o;
    for (int i = t; i < nel/4; i += TPB) dst[i] = src[i];
  } else {
    const uint4* src = (const uint4*)((const bf16*)p.outs + (size_t)b*AA*6 + (size_t)c*(TPB*6));
    for (int i = t; i < nel/8; i += TPB){
      uint4 u = src[i];
      int o = i*8;
      s_o[o+0]=__uint_as_float(u.x<<16); s_o[o+1]=__uint_as_float(u.x&0xffff0000u);
      s_o[o+2]=__uint_as_float(u.y<<16); s_o[o+3]=__uint_as_float(u.y&0xffff0000u);
      s_o[o+4]=__uint_as_float(u.z<<16); s_o[o+5]=__uint_as_float(u.z&0xffff0000u);
      s_o[o+6]=__uint_as_float(u.w<<16); s_o[o+7]=__uint_as_float(u.w&0xffff0000u);
    }
  }
  __syncthreads();
  if (t < GG){
    int i = b*GG + t;
    float l0 = ld(p.labs, i*5  , isf);
    float gcx= ld(p.labs, i*5+1, isf);
    float gcy= ld(p.labs, i*5+2, isf);
    float gw = ld(p.labs, i*5+3, isf);
    float gh = ld(p.labs, i*5+4, isf);
    int valid = (l0+gcx+gcy+gw+gh) > 0.f;
    float4 vb = make_float4(gcx-gw*0.5f, gcy-gh*0.5f, gcx+gw*0.5f, gcy+gh*0.5f);
    float4 vc = make_float4(gcx, gcy, gw*gh, valid ? 1.f : 0.f);
    s_gtb[t] = vb; s_gtc[t] = vc;
    if (c == 0){ p.gtb[i] = vb; p.gtc[i] = vc; }
    if (valid) atomicMax(&s_ng, t+1);
  }
  __syncthreads();
  int ng = s_ng;
  if (c == 0 && t == 0) p.gmax[b] = ng;
  int a = c*TPB + t;
  if (a < AA){
    float cx=s_o[t*6], cy=s_o[t*6+1], w=s_o[t*6+2], h=s_o[t*6+3], ob=s_o[t*6+4], cl=s_o[t*6+5];
    int idx = b*AA + a;
    p.box4[idx] = make_float4(cx-w*0.5f, cy-h*0.5f, cx+w*0.5f, cy+h*0.5f);
    float so = 1.f/(1.f+expf(-ob));
    float sc = 1.f/(1.f+expf(-cl));
    float pccv = -logf(sqrtf(sc*so) + 1e-9f);
    float xc, yc, r; ageom(a, xc, yc, r);
    int fg = 0;
    for (int g = 0; g < ng; ++g){
      float4 gb = s_gtb[g], gc = s_gtc[g];
      bool inb = (xc>gb.x)&&(xc<gb.z)&&(yc>gb.y)&&(yc<gb.w);
      bool inc = (fabsf(xc-gc.x)<r)&&(fabsf(yc-gc.y)<r);
      fg |= (gc.w != 0.f) && (inb||inc);
      if (fg) break;                        // OR: identical result
    }
    float area = w*h;                       // >= 16 (w,h >= 4): sign trick safe
    p.aux2[idx] = make_float2(fg ? area : -area, __uint_as_float(apack2(a)));
    p.pcc[idx] = pccv;
    p.zl [idx] = cl;
    p.cnt[idx] = 0;
    p.own[idx] = 0x7fffffff;
  }
}

// ---- kS: anchor-major screen ----------------------------------------------
// v18: inverts kB's loop. kB read 322MB (every gt re-read the image's anchor
// stream; L2-latency-bound at 45-50% VALU, 57us floor). kS loads each
// anchor's aux2/box4 ONCE into registers (4 anchors/lane; 6.3MB total) and
// tests it against all gts (wave w owns gts w, w+4, ...). Per (chunk,gt):
// wave-local top-10 by pop-extraction (static 4-reg remove), written to
// top10[(b,g),c]; geo hits appended to the global per-(b,g) list (wave-
// aggregated atomics; order-free -- selection is (cost,pos) lex, validated
// order-invariant since r5). Identical float expressions -> identical
// value multisets.
__global__ __launch_bounds__(TPB) void kS(P p){
  __shared__ float4 s_gtb[GG], s_gtc[GG];
  int t = threadIdx.x;
  int c = blockIdx.x, b = blockIdx.y;
  int lane = t & 63, wid = t >> 6;
  if (t < GG){ s_gtb[t] = p.gtb[b*GG+t]; s_gtc[t] = p.gtc[b*GG+t]; }
  __syncthreads();
  int ng = p.gmax[b];
  int base = b*AA;
  int a0 = c*TPB;
  float2 ax[4]; float4 bxr[4];
#pragma unroll
  for (int q=0;q<4;q++){
    int a = a0 + q*64 + lane;
    if (a < AA){ ax[q] = p.aux2[base+a]; bxr[q] = p.box4[base+a]; }
    else { ax[q] = make_float2(-1.f, 0.f); bxr[q] = make_float4(0,0,0,0); }
  }
  unsigned long long lmlt = (1ull<<lane) - 1ull;

  for (int g = wid; g < ng; g += 4){
    float4 gc = s_gtc[g];
    if (gc.w == 0.f) continue;              // kM skips invalid items too
    float4 gb = s_gtb[g];
    float glx=gb.x, gly=gb.y, ghx=gb.z, ghy=gb.w, gcx=gc.x, gcy=gc.y, ga=gc.z;
    float v[4];
#pragma unroll
    for (int q=0;q<4;q++){
      float2 aux = ax[q]; float4 bb = bxr[q];
      bool fg = aux.x > 0.f;
      uint32_t u = __float_as_uint(aux.y);
      float xc = (float)(u & 1023u), yc = (float)((u>>10)&1023u);
      float r  = (float)(20u << (u>>20));
      bool inb = (xc>glx)&&(xc<ghx)&&(yc>gly)&&(yc<ghy);
      bool geo = inb && (fabsf(xc-gcx)<r) && (fabsf(yc-gcy)<r);   // geo => fg
      float tlx=fmaxf(glx,bb.x), tly=fmaxf(gly,bb.y);
      float brx=fminf(ghx,bb.z), bry=fminf(ghy,bb.w);
      float iw=brx-tlx, ih=bry-tly;
      bool ovl = fg && (iw>0.f) && (ih>0.f);
      float vv = 0.f;
      if (ovl | geo){
        float area = fabsf(aux.x);
        float inter = fmaxf(iw,0.f)*fmaxf(ih,0.f);
        vv = inter/(ga + area - inter + 1e-12f);
      }
      v[q] = ovl ? vv : 0.f;                // 0 = not a positive
      unsigned long long m2 = __ballot(geo);
      if (m2){
        int ldr = (int)(__ffsll(m2)-1);
        int off;
        if (lane == ldr) off = atomicAdd(&p.gct[b*GG+g], __popcll(m2));
        off = __shfl(off, ldr);
        if (geo){
          int a = a0 + q*64 + lane;
          float cst = p.pcc[base+a] + 3.f*(-logf(vv+1e-8f));
          int qq = off + __popcll(m2 & lmlt);
          p.gcostL[(size_t)(b*GG+g)*GCAP + qq] = cst;
          p.gposL [(size_t)(b*GG+g)*GCAP + qq] = a;
        }
      }
    }
    // wave top-10 (descending) over v[0..3] x 64 lanes -> top10[(b,g),c]
    float* dst = &p.top10[((size_t)(b*GG+g)*NCH + c)*10];
    float lmax = fmaxf(fmaxf(v[0],v[1]), fmaxf(v[2],v[3]));
    int k = 0;
    for (; k < 10; ++k){
      float gv = lmax;
#pragma unroll
      for (int off=32; off; off>>=1) gv = fmaxf(gv, __shfl_xor(gv, off));
      if (gv <= 0.f) break;                 // usually immediately (sparse)
      if (lane == 0) dst[k] = gv;
      unsigned long long ms = __ballot(lmax == gv);
      if ((int)(__ffsll(ms)-1) == lane){    // unique owner: static remove
        bool fnd = false; float nl = 0.f;
#pragma unroll
        for (int q=0;q<4;q++){
          float vv = v[q];
          if (!fnd && vv == gv){ fnd = true; vv = 0.f; v[q] = vv; }
          nl = fmaxf(nl, vv);
        }
        lmax = nl;
      }
    }
    if (lane == 0) for (int kk=k; kk<10; ++kk) dst[kk] = 0.f;
  }
}

// ---- kM: per-(b,g) merge + dyn_k + selection (grid 3200, 1 wave) ----------
// v18: pop-merges 330 partials (top-10 of union of per-chunk top-10s ==
// global top-10; descending pop order == r14's -> bit-exact dk), then r14's
// selection verbatim over the geo list + rare non-geo fallback. Writes
// slots + cnt/own atomics (commutative, deterministic owner).
__global__ __launch_bounds__(64) void kM(P p){
  int lane = threadIdx.x;
  int item = blockIdx.x;
  int b = item / GG, g = item - b*GG;
  float4 gc = p.gtc[item];
  if (gc.w == 0.f) return;
  float4 gb = p.gtb[item];
  float glx=gb.x, gly=gb.y, ghx=gb.z, ghy=gb.w, gcx=gc.x, gcy=gc.y, ga=gc.z;
  int base = b*AA;

  // load 330 partials into 6 static registers/lane
  float r6[6];
#pragma unroll
  for (int q=0;q<6;q++){
    int i = q*64 + lane;
    r6[q] = (i < NT10) ? p.top10[(size_t)item*NT10 + i] : 0.f;
  }
  float lmax = 0.f;
#pragma unroll
  for (int q=0;q<6;q++) lmax = fmaxf(lmax, r6[q]);
  float sum = 0.f;
  for (int k = 0; k < 10; ++k){
    float gv = lmax;
#pragma unroll
    for (int off=32; off; off>>=1) gv = fmaxf(gv, __shfl_xor(gv, off));
    if (gv <= 0.f) break;
    sum += gv;
    unsigned long long ms = __ballot(lmax == gv);
    if ((int)(__ffsll(ms)-1) == lane){      // unique owner: static remove
      bool fnd = false; float nl = 0.f;
#pragma unroll
      for (int q=0;q<6;q++){
        float vv = r6[q];
        if (!fnd && vv == gv){ fnd = true; vv = 0.f; r6[q] = vv; }
        nl = fmaxf(nl, vv);
      }
      lmax = nl;
    }
  }
  int dk = (int)sum; if (dk<1) dk=1; if (dk>10) dk=10;

  // selection among geo (<=2 entries/lane; all geo < all non-geo cost)
  int gcnt = p.gct[item];                   // <= 75 < GCAP
  float c0=3.0e38f, c1=3.0e38f; int p0=0x7fffffff, p1=0x7fffffff;
  if (lane < gcnt){ c0 = p.gcostL[(size_t)item*GCAP+lane]; p0 = p.gposL[(size_t)item*GCAP+lane]; }
  if (lane+64 < gcnt){ c1 = p.gcostL[(size_t)item*GCAP+lane+64]; p1 = p.gposL[(size_t)item*GCAP+lane+64]; }
  if (c1 < c0 || (c1==c0 && p1<p0)){
    float tc=c0; c0=c1; c1=tc; int tp=p0; p0=p1; p1=tp;
  }
  int mysel = -1, take = 0;
  for (int k = 0; k < dk; ++k){
    float gv=c0; int gi=p0;
#pragma unroll
    for (int off=32; off; off>>=1){
      float ov=__shfl_xor(gv,off); int oi=__shfl_xor(gi,off);
      if (ov<gv || (ov==gv && oi<gi)){ gv=ov; gi=oi; }
    }
    if (gv >= 2.9e38f) break;               // geo exhausted
    if (lane == k) mysel = gi;
    take++;
    if (c0==gv && p0==gi){ c0=c1; p0=p1; c1=3.0e38f; p1=0x7fffffff; }
  }

  // rare fallback: need (dk-take) non-geo picks; exact k-th smallest via
  // repeated rescan excluding previous picks by strict lex >
  float lastc = -3.0e38f; int lastp = -1;
  for (int k = take; k < dk; ++k){
    float bc = 3.0e38f; int bp = 0x7fffffff;
    int n64 = (AA + 63) >> 6;
    for (int it = 0; it < n64; ++it){
      int pos = (it<<6) + lane;
      if (pos < AA){
        float2 aux = p.aux2[base+pos];
        bool fg = aux.x > 0.f;
        if (fg){
          uint32_t u = __float_as_uint(aux.y);
          float xc = (float)(u & 1023u), yc = (float)((u>>10)&1023u);
          float r  = (float)(20u << (u>>20));
          bool inb = (xc>glx)&&(xc<ghx)&&(yc>gly)&&(yc<ghy);
          bool geo2 = inb && (fabsf(xc-gcx)<r) && (fabsf(yc-gcy)<r);
          if (!geo2){
            float4 bx = p.box4[base+pos];
            float tlx=fmaxf(glx,bx.x), tly=fmaxf(gly,bx.y);
            float brx=fminf(ghx,bx.z), bry=fminf(ghy,bx.w);
            float iw=fmaxf(brx-tlx,0.f), ih=fmaxf(bry-tly,0.f);
            float inter=iw*ih;
            float area = fabsf(aux.x);
            float v = inter/(ga + area - inter + 1e-12f);
            float cst = p.pcc[base+pos] + 3.f*(-logf(v+1e-8f)) + 100000.f;
            bool gt = (cst > lastc) || (cst == lastc && pos > lastp);
            bool lt = (cst < bc)   || (cst == bc   && pos < bp);
            if (gt && lt){ bc = cst; bp = pos; }
          }
        }
      }
    }
#pragma unroll
    for (int off=32; off; off>>=1){
      float ov=__shfl_xor(bc,off); int oi=__shfl_xor(bp,off);
      if (ov<bc || (ov==bc && oi<bp)){ bc=ov; bp=oi; }
    }
    if (bc >= 2.9e38f) break;               // candidates exhausted
    if (lane == k) mysel = bp;
    lastc = bc; lastp = bp;
  }

  if (mysel >= 0){                          // lanes 0..dk-1 hold selections
    int a = mysel;
    float4 bx = p.box4[base+a];
    float area = fabsf(p.aux2[base+a].x);
    float tlx=fmaxf(glx,bx.x), tly=fmaxf(gly,bx.y);
    float brx=fminf(ghx,bx.z), bry=fminf(ghy,bx.w);
    float iw=fmaxf(brx-tlx,0.f), ih=fmaxf(bry-tly,0.f);
    float inter=iw*ih;
    float iou=inter/(ga + area - inter + 1e-12f);
    int slot = g*10 + lane;                 // deterministic slot id
    p.sel_a [b*SCAP + slot] = a;
    p.sel_iou[b*SCAP + slot] = iou;
    atomicAdd(&p.cnt[base+a], 1);
    atomicMin(&p.own[base+a], slot);        // commutative -> deterministic owner
  }
}

// ---- kR: per-(b,g) resolution + BCE partials (r14 verbatim) ---------------
__global__ __launch_bounds__(64) void kR(P p){
  int lane = threadIdx.x;
  int item = blockIdx.x;
  int b = item / GG, g = item - b*GG;
  int base = b*AA;
  int a = -1, cgt = 0;
  bool ownr = false;
  float iouv = 0.f;
  if (lane < 10){
    int slot = g*10 + lane;
    a = p.sel_a[b*SCAP + slot];
    if (a >= 0 && p.own[base+a] == slot){
      ownr = true;
      cgt = p.cnt[base+a];
      iouv = p.sel_iou[b*SCAP + slot];      // final value when cgt==1
    }
  }
  unsigned long long cm = __ballot(ownr && cgt > 1);
  if (cm){
    int ng = p.gmax[b];
    while (cm){
      int s = (int)(__ffsll(cm)-1); cm &= cm - 1ull;
      int aa = __shfl(a, s);
      float area = fabsf(p.aux2[base+aa].x);
      float pccv = p.pcc[base+aa];
      float4 bx = p.box4[base+aa];
      float xc,yc,r; ageom(aa,xc,yc,r);
      float bc = 3.9e38f, bi = 0.f; int bg = 0x7fffffff;
      for (int g2 = lane; g2 < ng; g2 += 64){
        float4 gbb = p.gtb[b*GG+g2], gcc = p.gtc[b*GG+g2];
        float cost, iou2 = 0.f;
        if (gcc.w != 0.f){
          float tlx=fmaxf(gbb.x,bx.x), tly=fmaxf(gbb.y,bx.y);
          float brx=fminf(gbb.z,bx.z), bry=fminf(gbb.w,bx.w);
          float iw=fmaxf(brx-tlx,0.f), ih=fmaxf(bry-tly,0.f);
          float inter=iw*ih;
          iou2 = inter/(gcc.z + area - inter + 1e-12f);
          bool inb=(xc>gbb.x)&&(xc<gbb.z)&&(yc>gbb.y)&&(yc<gbb.w);
          bool inc=(fabsf(xc-gcc.x)<r)&&(fabsf(yc-gcc.y)<r);
          cost = pccv + 3.f*(-logf(iou2+1e-8f)) + ((inb&&inc)?0.f:100000.f);
        } else cost = 1e9f;
        if (cost < bc){ bc=cost; bi=iou2; bg=g2; }   // lane-local first-min
      }
#pragma unroll
      for (int off=32; off; off>>=1){
        float oc=__shfl_xor(bc,off), oi=__shfl_xor(bi,off);
        int og=__shfl_xor(bg,off);
        if (oc<bc || (oc==bc && og<bg)){ bc=oc; bi=oi; bg=og; }
      }
      if (lane == s) iouv = bi;             // deliver to owning lane
    }
  }
  float bce = 0.f, fgv = 0.f;
  if (lane < 10 && ownr){
    float z = p.zl[base+a];
    float e = expf(-fabsf(z));
    float spz = fmaxf(z,0.f)+log1pf(e);
    float spn = fmaxf(-z,0.f)+log1pf(e);
    bce = iouv*spn + (1.f-iouv)*spz;
    fgv = 1.f;
  }
#pragma unroll
  for (int off=32; off; off>>=1){
    bce += __shfl_xor(bce, off);
    fgv += __shfl_xor(fgv, off);
  }
  if (lane == 0){ p.pb[item] = bce; p.pf[item] = fgv; }
}

// ---- kD: reduce 3200 partials + finalize (1 block) -------------------------
__global__ __launch_bounds__(TPB) void kD(P p){
  int t = threadIdx.x;
  float sb=0.f, sf=0.f;
  for (int i = t; i < NB2; i += TPB){ sb += p.pb[i]; sf += p.pf[i]; }
#pragma unroll
  for (int off=32; off; off>>=1){
    sb += __shfl_xor(sb, off);
    sf += __shfl_xor(sf, off);
  }
  __shared__ float s_b[4], s_f[4];
  int lane = t & 63, wid = t >> 6;
  if (lane==0){ s_b[wid]=sb; s_f[wid]=sf; }
  __syncthreads();
  if (t==0){
    float tb=s_b[0]+s_b[1]+s_b[2]+s_b[3];
    float tf=s_f[0]+s_f[1]+s_f[2]+s_f[3];
    p.out[0] = tb / fmaxf(tf, 1.f);
  }
}

extern "C" void kernel_launch(void* const* d_in, const int* in_sizes, int n_in,
                              void* d_out, int out_size, void* d_ws, size_t ws_size,
                              hipStream_t stream) {
  P p;
  p.outs = d_in[0];
  p.labs = d_in[1];
  p.ss   = d_in[4];
  char* w = (char*)d_ws;
  p.box4  = (float4*)w; w += (size_t)BA*sizeof(float4);
  p.gtb   = (float4*)w; w += (size_t)NG*sizeof(float4);
  p.gtc   = (float4*)w; w += (size_t)NG*sizeof(float4);
  p.aux2  = (float2*)w; w += (size_t)BA*sizeof(float2);
  p.pcc   = (float*)w;  w += (size_t)BA*sizeof(float);
  p.zl    = (float*)w;  w += (size_t)BA*sizeof(float);
  p.top10 = (float*)w;  w += (size_t)NB2*NT10*sizeof(float);
  p.gcostL= (float*)w;  w += (size_t)NB2*GCAP*sizeof(float);
  p.gposL = (int*)w;    w += (size_t)NB2*GCAP*sizeof(int);
  p.gct   = (int*)w;    w += (size_t)NB2*sizeof(int);
  p.sel_a = (int*)w;    w += (size_t)BB*SCAP*sizeof(int);
  p.sel_iou=(float*)w;  w += (size_t)BB*SCAP*sizeof(float);
  p.cnt   = (int*)w;    w += (size_t)BA*sizeof(int);
  p.own   = (int*)w;    w += (size_t)BA*sizeof(int);
  p.gmax  = (int*)w;    w += (size_t)BB*sizeof(int);
  p.pb    = (float*)w;  w += (size_t)NB2*sizeof(float);
  p.pf    = (float*)w;  w += (size_t)NB2*sizeof(float);
  p.out   = (float*)d_out;

  kA<<<dim3(NCH, BB), TPB, 0, stream>>>(p);
  kS<<<dim3(NCH, BB), TPB, 0, stream>>>(p);
  kM<<<NB2, 64, 0, stream>>>(p);
  kR<<<NB2, 64, 0, stream>>>(p);
  kD<<<1, TPB, 0, stream>>>(p);
}

// Round 18
// 165.943 us; speedup vs baseline: 1.3903x; 1.3903x over previous
//
#include <hip/hip_runtime.h>
#include <hip/hip_bf16.h>
#include <stdint.h>

#define BB 32
#define GG 100
#define AA 8400
#define TPB 256
#define NCH 33                         // ceil(8400/256) chunks per image
#define TKB 512                        // kSp block size (8 waves)
#define NSP 4                          // spans per gt
#define SPAN (AA/NSP)                  // 2100 anchors per span
#define NITS 5                         // ceil(SPAN/TKB)
#define BA (BB*AA)
#define NG (BB*GG)
#define NB2 (BB*GG)                    // items
#define SCAP2 2112                     // span positives cap
#define GCAP 128                       // geo cap (provably <= 75 per gt)
#define SCAP (GG*10)                   // selection slots per image (g*10+k)
#define NT10 (NSP*10)                  // 40 top-10 partials per item

typedef __hip_bfloat16 bf16;

struct P {
  const void *outs, *labs, *ss;
  float4 *box4, *gtb, *gtc;           // per-anchor box; per-gt box/center
  float2 *aux2;                       // per-anchor (fg? area : -area, cpk bits)
  float *pcc, *zl;                    // per-anchor cls-cost / cls logit
  float *top10;                       // [NB2][NSP][10] per-span top-10 ious
  float *gcostL;                      // [NB2][GCAP] geo costs
  int   *gposL;                       // [NB2][GCAP] geo anchor ids
  int   *gct;                         // [NB2] geo counts
  int   *sel_a;                       // [BB][SCAP] selected anchor id, -1 empty
  float *sel_iou;                     // [BB][SCAP] its iou
  int   *cnt, *own;                   // per-anchor selection count / min slot
  float *pb, *pf;                     // per-(b,g) BCE / fg partials
  int *gmax;
  float *out;
};

// runtime input-dtype detection: strides[0]==8.0
// f32 word 0x41000000 ; bf16 pair (8.0,8.0) 0x41004100
__device__ __forceinline__ int dtypeFlag(const void* ss){
  return (((const uint32_t*)ss)[0] == 0x41000000u) ? 1 : 0;
}
__device__ __forceinline__ float ld(const void* p, int i, int isf32){
  return isf32 ? ((const float*)p)[i] : __bfloat162float(((const bf16*)p)[i]);
}
// analytic anchor geometry (exact: ints + pow2 strides exact in f32/bf16)
__device__ __forceinline__ void ageom(int a, float& xc, float& yc, float& r){
  int x, y, s;
  if (a < 6400){ x = a % 80; y = a / 80; s = 8; }
  else if (a < 8000){ int q = a - 6400; x = q % 40; y = q / 40; s = 16; }
  else { int q = a - 8000; x = q % 20; y = q / 20; s = 32; }
  float fs = (float)s;
  xc = ((float)x + 0.5f) * fs;
  yc = ((float)y + 0.5f) * fs;
  r  = 2.5f * fs;
}
// pack integer center + level: xc(10) | yc(10)<<10 | lvl<<20
__device__ __forceinline__ uint32_t apack2(int a){
  int x, y, s, lvl;
  if (a < 6400){ x = a % 80; y = a / 80; s = 8; lvl = 0; }
  else if (a < 8000){ int q = a - 6400; x = q % 40; y = q / 40; s = 16; lvl = 1; }
  else { int q = a - 8000; x = q % 20; y = q / 20; s = 32; lvl = 2; }
  return (uint32_t)(x*s + s/2) | ((uint32_t)(y*s + s/2) << 10) | ((uint32_t)lvl << 20);
}

// ---- kA: gt structs + per-anchor staging + fg (r14 verbatim + gct init) ---
__global__ __launch_bounds__(TPB) void kA(P p){
  __shared__ float4 s_gtb[GG], s_gtc[GG];
  __shared__ float s_o[TPB*6];
  __shared__ int s_ng;
  int t = threadIdx.x;
  int c = blockIdx.x, b = blockIdx.y;
  int isf = dtypeFlag(p.ss);
  if (t == 0) s_ng = 0;
  {
    int s = c*TPB + t;
    if (s < SCAP) p.sel_a[b*SCAP + s] = -1;        // empty slot marker
    if (s < GG)   p.gct[b*GG + s] = 0;             // geo list counter
  }
  int nel = min(TPB*6, AA*6 - c*(TPB*6));      // floats in this chunk
  if (isf){
    const float4* src = (const float4*)((const float*)p.outs + (size_t)b*AA*6 + (size_t)c*(TPB*6));
    float4* dst = (float4*)s_o;
    for (int i = t; i < nel/4; i += TPB) dst[i] = src[i];
  } else {
    const uint4* src = (const uint4*)((const bf16*)p.outs + (size_t)b*AA*6 + (size_t)c*(TPB*6));
    for (int i = t; i < nel/8; i += TPB){
      uint4 u = src[i];
      int o = i*8;
      s_o[o+0]=__uint_as_float(u.x<<16); s_o[o+1]=__uint_as_float(u.x&0xffff0000u);
      s_o[o+2]=__uint_as_float(u.y<<16); s_o[o+3]=__uint_as_float(u.y&0xffff0000u);
      s_o[o+4]=__uint_as_float(u.z<<16); s_o[o+5]=__uint_as_float(u.z&0xffff0000u);
      s_o[o+6]=__uint_as_float(u.w<<16); s_o[o+7]=__uint_as_float(u.w&0xffff0000u);
    }
  }
  __syncthreads();
  if (t < GG){
    int i = b*GG + t;
    float l0 = ld(p.labs, i*5  , isf);
    float gcx= ld(p.labs, i*5+1, isf);
    float gcy= ld(p.labs, i*5+2, isf);
    float gw = ld(p.labs, i*5+3, isf);
    float gh = ld(p.labs, i*5+4, isf);
    int valid = (l0+gcx+gcy+gw+gh) > 0.f;
    float4 vb = make_float4(gcx-gw*0.5f, gcy-gh*0.5f, gcx+gw*0.5f, gcy+gh*0.5f);
    float4 vc = make_float4(gcx, gcy, gw*gh, valid ? 1.f : 0.f);
    s_gtb[t] = vb; s_gtc[t] = vc;
    if (c == 0){ p.gtb[i] = vb; p.gtc[i] = vc; }
    if (valid) atomicMax(&s_ng, t+1);
  }
  __syncthreads();
  int ng = s_ng;
  if (c == 0 && t == 0) p.gmax[b] = ng;
  int a = c*TPB + t;
  if (a < AA){
    float cx=s_o[t*6], cy=s_o[t*6+1], w=s_o[t*6+2], h=s_o[t*6+3], ob=s_o[t*6+4], cl=s_o[t*6+5];
    int idx = b*AA + a;
    p.box4[idx] = make_float4(cx-w*0.5f, cy-h*0.5f, cx+w*0.5f, cy+h*0.5f);
    float so = 1.f/(1.f+expf(-ob));
    float sc = 1.f/(1.f+expf(-cl));
    float pccv = -logf(sqrtf(sc*so) + 1e-9f);
    float xc, yc, r; ageom(a, xc, yc, r);
    int fg = 0;
    for (int g = 0; g < ng; ++g){
      float4 gb = s_gtb[g], gc = s_gtc[g];
      bool inb = (xc>gb.x)&&(xc<gb.z)&&(yc>gb.y)&&(yc<gb.w);
      bool inc = (fabsf(xc-gc.x)<r)&&(fabsf(yc-gc.y)<r);
      fg |= (gc.w != 0.f) && (inb||inc);
      if (fg) break;                        // OR: identical result
    }
    float area = w*h;                       // >= 16 (w,h >= 4): sign trick safe
    p.aux2[idx] = make_float2(fg ? area : -area, __uint_as_float(apack2(a)));
    p.pcc[idx] = pccv;
    p.zl [idx] = cl;
    p.cnt[idx] = 0;
    p.own[idx] = 0x7fffffff;
  }
}

// ---- kSp: span screen (kB's fast screen shape, 1/4 range, 4x blocks) ------
// v19: r17 post-mortem -- kS's anchor-major inversion cut worker-waves 3x
// and tripled per-pair overhead (121us). This keeps kB's VERBATIM screen
// body (same streams, LDS push, wave-0 pop) but each block handles one
// 2100-anchor span of one gt: 12800 blocks (smoother tail, the r12
// occupancy diagnosis), 1/4 per-block critical path. Wave 0 pops the span
// top-10 into top10[item][h]; geo hits go to the r17-PROVEN global list
// (racy order OK: (cost,pos) lex selection is order-invariant, absmax 0).
__global__ __launch_bounds__(TKB) void kSp(P p){
  __shared__ float s_pos[SCAP2];
  __shared__ int   s_pcnt;
  int t = threadIdx.x;
  int lane = t & 63, wid = t >> 6;
  int bid = blockIdx.x;
  int item = bid >> 2, h = bid & 3;
  int b = item / GG, g = item - b*GG;
  if (t == 0) s_pcnt = 0;
  float4 gc = p.gtc[item];
  if (gc.w == 0.f) return;                  // uniform exit, pre-barrier
  float4 gb = p.gtb[item];
  float glx=gb.x, gly=gb.y, ghx=gb.z, ghy=gb.w, gcx=gc.x, gcy=gc.y, ga=gc.z;
  int base = b*AA;
  int lo = h*SPAN, hi = lo + SPAN;          // hi <= AA
  unsigned long long lmlt = (1ull<<lane) - 1ull;
  __syncthreads();                          // s_pcnt init visible

  for (int it = 0; it < NITS; ++it){
    int pos = lo + it*TKB + t;
    bool ovl = false, geo = false;
    float v = 0.f, cst = 0.f;
    if (pos < hi){
      float2 aux = p.aux2[base+pos];
      float4 bx  = p.box4[base+pos];
      bool fg = aux.x > 0.f;
      uint32_t u = __float_as_uint(aux.y);
      float xc = (float)(u & 1023u), yc = (float)((u>>10)&1023u);
      float r  = (float)(20u << (u>>20));
      bool inb = (xc>glx)&&(xc<ghx)&&(yc>gly)&&(yc<ghy);
      geo = inb && (fabsf(xc-gcx)<r) && (fabsf(yc-gcy)<r);   // geo => fg
      float tlx=fmaxf(glx,bx.x), tly=fmaxf(gly,bx.y);
      float brx=fminf(ghx,bx.z), bry=fminf(ghy,bx.w);
      float iw=brx-tlx, ih=bry-tly;
      ovl = fg && (iw>0.f) && (ih>0.f);
      if (ovl | geo){
        float area = fabsf(aux.x);
        float inter = fmaxf(iw,0.f)*fmaxf(ih,0.f);
        v = inter/(ga + area - inter + 1e-12f);
        if (geo) cst = p.pcc[base+pos] + 3.f*(-logf(v+1e-8f));
      }
    }
    unsigned long long m1 = __ballot(ovl);
    if (m1){
      int ldr = (int)(__ffsll(m1)-1);
      int off;
      if (lane == ldr) off = atomicAdd(&s_pcnt, __popcll(m1));
      off = __shfl(off, ldr);
      if (ovl) s_pos[off + __popcll(m1 & lmlt)] = v;
    }
    unsigned long long m2 = __ballot(geo);
    if (m2){
      int ldr = (int)(__ffsll(m2)-1);
      int off;
      if (lane == ldr) off = atomicAdd(&p.gct[item], __popcll(m2));
      off = __shfl(off, ldr);
      if (geo){
        int q = off + __popcll(m2 & lmlt);
        p.gcostL[(size_t)item*GCAP + q] = cst;
        p.gposL [(size_t)item*GCAP + q] = pos;
      }
    }
  }
  __syncthreads();
  if (wid) return;                          // 7 waves released; wave 0 pops

  int pcnt = s_pcnt;
  float* dst = &p.top10[(size_t)item*NT10 + h*10];
  float lmax = -1.f;
  for (int i = lane; i < pcnt; i += 64) lmax = fmaxf(lmax, s_pos[i]);
  int k = 0;
  for (; k < 10; ++k){
    float gv = lmax;
#pragma unroll
    for (int off=32; off; off>>=1) gv = fmaxf(gv, __shfl_xor(gv, off));
    if (gv <= 0.f) break;
    if (lane == 0) dst[k] = gv;
    unsigned long long ms = __ballot(lmax == gv);
    if ((int)(__ffsll(ms)-1) == lane){      // unique owner: remove 1 instance
      bool fnd = false; float nl = -1.f;
      for (int i = lane; i < pcnt; i += 64){
        float vv = s_pos[i];
        if (!fnd && vv == gv){ fnd = true; vv = -1.f; s_pos[i] = vv; }
        nl = fmaxf(nl, vv);
      }
      lmax = nl;
    }
  }
  if (lane == 0) for (int kk=k; kk<10; ++kk) dst[kk] = 0.f;
}

// ---- kM: per-item merge + dyn_k + selection (r17-proven, NT10=40) ---------
__global__ __launch_bounds__(64) void kM(P p){
  int lane = threadIdx.x;
  int item = blockIdx.x;
  int b = item / GG, g = item - b*GG;
  float4 gc = p.gtc[item];
  if (gc.w == 0.f) return;
  float4 gb = p.gtb[item];
  float glx=gb.x, gly=gb.y, ghx=gb.z, ghy=gb.w, gcx=gc.x, gcy=gc.y, ga=gc.z;
  int base = b*AA;

  // 40 partials: one register per lane; exact descending merged pops
  float r0 = (lane < NT10) ? p.top10[(size_t)item*NT10 + lane] : 0.f;
  float sum = 0.f;
  for (int k = 0; k < 10; ++k){
    float gv = r0;
#pragma unroll
    for (int off=32; off; off>>=1) gv = fmaxf(gv, __shfl_xor(gv, off));
    if (gv <= 0.f) break;
    sum += gv;
    unsigned long long ms = __ballot(r0 == gv);
    if ((int)(__ffsll(ms)-1) == lane) r0 = 0.f;   // remove one instance
  }
  int dk = (int)sum; if (dk<1) dk=1; if (dk>10) dk=10;

  // selection among geo (<=2 entries/lane; all geo < all non-geo cost)
  int gcnt = p.gct[item];                   // <= 75 < GCAP
  float c0=3.0e38f, c1=3.0e38f; int p0=0x7fffffff, p1=0x7fffffff;
  if (lane < gcnt){ c0 = p.gcostL[(size_t)item*GCAP+lane]; p0 = p.gposL[(size_t)item*GCAP+lane]; }
  if (lane+64 < gcnt){ c1 = p.gcostL[(size_t)item*GCAP+lane+64]; p1 = p.gposL[(size_t)item*GCAP+lane+64]; }
  if (c1 < c0 || (c1==c0 && p1<p0)){
    float tc=c0; c0=c1; c1=tc; int tp=p0; p0=p1; p1=tp;
  }
  int mysel = -1, take = 0;
  for (int k = 0; k < dk; ++k){
    float gv=c0; int gi=p0;
#pragma unroll
    for (int off=32; off; off>>=1){
      float ov=__shfl_xor(gv,off); int oi=__shfl_xor(gi,off);
      if (ov<gv || (ov==gv && oi<gi)){ gv=ov; gi=oi; }
    }
    if (gv >= 2.9e38f) break;               // geo exhausted
    if (lane == k) mysel = gi;
    take++;
    if (c0==gv && p0==gi){ c0=c1; p0=p1; c1=3.0e38f; p1=0x7fffffff; }
  }

  // rare fallback: need (dk-take) non-geo picks; exact k-th smallest via
  // repeated rescan excluding previous picks by strict lex >
  float lastc = -3.0e38f; int lastp = -1;
  for (int k = take; k < dk; ++k){
    float bc = 3.0e38f; int bp = 0x7fffffff;
    int n64 = (AA + 63) >> 6;
    for (int it = 0; it < n64; ++it){
      int pos = (it<<6) + lane;
      if (pos < AA){
        float2 aux = p.aux2[base+pos];
        bool fg = aux.x > 0.f;
        if (fg){
          uint32_t u = __float_as_uint(aux.y);
          float xc = (float)(u & 1023u), yc = (float)((u>>10)&1023u);
          float r  = (float)(20u << (u>>20));
          bool inb = (xc>glx)&&(xc<ghx)&&(yc>gly)&&(yc<ghy);
          bool geo2 = inb && (fabsf(xc-gcx)<r) && (fabsf(yc-gcy)<r);
          if (!geo2){
            float4 bx = p.box4[base+pos];
            float tlx=fmaxf(glx,bx.x), tly=fmaxf(gly,bx.y);
            float brx=fminf(ghx,bx.z), bry=fminf(ghy,bx.w);
            float iw=fmaxf(brx-tlx,0.f), ih=fmaxf(bry-tly,0.f);
            float inter=iw*ih;
            float area = fabsf(aux.x);
            float v = inter/(ga + area - inter + 1e-12f);
            float cst = p.pcc[base+pos] + 3.f*(-logf(v+1e-8f)) + 100000.f;
            bool gt = (cst > lastc) || (cst == lastc && pos > lastp);
            bool lt = (cst < bc)   || (cst == bc   && pos < bp);
            if (gt && lt){ bc = cst; bp = pos; }
          }
        }
      }
    }
#pragma unroll
    for (int off=32; off; off>>=1){
      float ov=__shfl_xor(bc,off); int oi=__shfl_xor(bp,off);
      if (ov<bc || (ov==bc && oi<bp)){ bc=ov; bp=oi; }
    }
    if (bc >= 2.9e38f) break;               // candidates exhausted
    if (lane == k) mysel = bp;
    lastc = bc; lastp = bp;
  }

  if (mysel >= 0){                          // lanes 0..dk-1 hold selections
    int a = mysel;
    float4 bx = p.box4[base+a];
    float area = fabsf(p.aux2[base+a].x);
    float tlx=fmaxf(glx,bx.x), tly=fmaxf(gly,bx.y);
    float brx=fminf(ghx,bx.z), bry=fminf(ghy,bx.w);
    float iw=fmaxf(brx-tlx,0.f), ih=fmaxf(bry-tly,0.f);
    float inter=iw*ih;
    float iou=inter/(ga + area - inter + 1e-12f);
    int slot = g*10 + lane;                 // deterministic slot id
    p.sel_a [b*SCAP + slot] = a;
    p.sel_iou[b*SCAP + slot] = iou;
    atomicAdd(&p.cnt[base+a], 1);
    atomicMin(&p.own[base+a], slot);        // commutative -> deterministic owner
  }
}

// ---- kR: per-(b,g) resolution + BCE partials (r14 verbatim) ---------------
__global__ __launch_bounds__(64) void kR(P p){
  int lane = threadIdx.x;
  int item = blockIdx.x;
  int b = item / GG, g = item - b*GG;
  int base = b*AA;
  int a = -1, cgt = 0;
  bool ownr = false;
  float iouv = 0.f;
  if (lane < 10){
    int slot = g*10 + lane;
    a = p.sel_a[b*SCAP + slot];
    if (a >= 0 && p.own[base+a] == slot){
      ownr = true;
      cgt = p.cnt[base+a];
      iouv = p.sel_iou[b*SCAP + slot];      // final value when cgt==1
    }
  }
  unsigned long long cm = __ballot(ownr && cgt > 1);
  if (cm){
    int ng = p.gmax[b];
    while (cm){
      int s = (int)(__ffsll(cm)-1); cm &= cm - 1ull;
      int aa = __shfl(a, s);
      float area = fabsf(p.aux2[base+aa].x);
      float pccv = p.pcc[base+aa];
      float4 bx = p.box4[base+aa];
      float xc,yc,r; ageom(aa,xc,yc,r);
      float bc = 3.9e38f, bi = 0.f; int bg = 0x7fffffff;
      for (int g2 = lane; g2 < ng; g2 += 64){
        float4 gbb = p.gtb[b*GG+g2], gcc = p.gtc[b*GG+g2];
        float cost, iou2 = 0.f;
        if (gcc.w != 0.f){
          float tlx=fmaxf(gbb.x,bx.x), tly=fmaxf(gbb.y,bx.y);
          float brx=fminf(gbb.z,bx.z), bry=fminf(gbb.w,bx.w);
          float iw=fmaxf(brx-tlx,0.f), ih=fmaxf(bry-tly,0.f);
          float inter=iw*ih;
          iou2 = inter/(gcc.z + area - inter + 1e-12f);
          bool inb=(xc>gbb.x)&&(xc<gbb.z)&&(yc>gbb.y)&&(yc<gbb.w);
          bool inc=(fabsf(xc-gcc.x)<r)&&(fabsf(yc-gcc.y)<r);
          cost = pccv + 3.f*(-logf(iou2+1e-8f)) + ((inb&&inc)?0.f:100000.f);
        } else cost = 1e9f;
        if (cost < bc){ bc=cost; bi=iou2; bg=g2; }   // lane-local first-min
      }
#pragma unroll
      for (int off=32; off; off>>=1){
        float oc=__shfl_xor(bc,off), oi=__shfl_xor(bi,off);
        int og=__shfl_xor(bg,off);
        if (oc<bc || (oc==bc && og<bg)){ bc=oc; bi=oi; bg=og; }
      }
      if (lane == s) iouv = bi;             // deliver to owning lane
    }
  }
  float bce = 0.f, fgv = 0.f;
  if (lane < 10 && ownr){
    float z = p.zl[base+a];
    float e = expf(-fabsf(z));
    float spz = fmaxf(z,0.f)+log1pf(e);
    float spn = fmaxf(-z,0.f)+log1pf(e);
    bce = iouv*spn + (1.f-iouv)*spz;
    fgv = 1.f;
  }
#pragma unroll
  for (int off=32; off; off>>=1){
    bce += __shfl_xor(bce, off);
    fgv += __shfl_xor(fgv, off);
  }
  if (lane == 0){ p.pb[item] = bce; p.pf[item] = fgv; }
}

// ---- kD: reduce 3200 partials + finalize (1 block) -------------------------
__global__ __launch_bounds__(TPB) void kD(P p){
  int t = threadIdx.x;
  float sb=0.f, sf=0.f;
  for (int i = t; i < NB2; i += TPB){ sb += p.pb[i]; sf += p.pf[i]; }
#pragma unroll
  for (int off=32; off; off>>=1){
    sb += __shfl_xor(sb, off);
    sf += __shfl_xor(sf, off);
  }
  __shared__ float s_b[4], s_f[4];
  int lane = t & 63, wid = t >> 6;
  if (lane==0){ s_b[wid]=sb; s_f[wid]=sf; }
  __syncthreads();
  if (t==0){
    float tb=s_b[0]+s_b[1]+s_b[2]+s_b[3];
    float tf=s_f[0]+s_f[1]+s_f[2]+s_f[3];
    p.out[0] = tb / fmaxf(tf, 1.f);
  }
}

extern "C" void kernel_launch(void* const* d_in, const int* in_sizes, int n_in,
                              void* d_out, int out_size, void* d_ws, size_t ws_size,
                              hipStream_t stream) {
  P p;
  p.outs = d_in[0];
  p.labs = d_in[1];
  p.ss   = d_in[4];
  char* w = (char*)d_ws;
  p.box4  = (float4*)w; w += (size_t)BA*sizeof(float4);
  p.gtb   = (float4*)w; w += (size_t)NG*sizeof(float4);
  p.gtc   = (float4*)w; w += (size_t)NG*sizeof(float4);
  p.aux2  = (float2*)w; w += (size_t)BA*sizeof(float2);
  p.pcc   = (float*)w;  w += (size_t)BA*sizeof(float);
  p.zl    = (float*)w;  w += (size_t)BA*sizeof(float);
  p.top10 = (float*)w;  w += (size_t)NB2*NT10*sizeof(float);
  p.gcostL= (float*)w;  w += (size_t)NB2*GCAP*sizeof(float);
  p.gposL = (int*)w;    w += (size_t)NB2*GCAP*sizeof(int);
  p.gct   = (int*)w;    w += (size_t)NB2*sizeof(int);
  p.sel_a = (int*)w;    w += (size_t)BB*SCAP*sizeof(int);
  p.sel_iou=(float*)w;  w += (size_t)BB*SCAP*sizeof(float);
  p.cnt   = (int*)w;    w += (size_t)BA*sizeof(int);
  p.own   = (int*)w;    w += (size_t)BA*sizeof(int);
  p.gmax  = (int*)w;    w += (size_t)BB*sizeof(int);
  p.pb    = (float*)w;  w += (size_t)NB2*sizeof(float);
  p.pf    = (float*)w;  w += (size_t)NB2*sizeof(float);
  p.out   = (float*)d_out;

  kA<<<dim3(NCH, BB), TPB, 0, stream>>>(p);
  kSp<<<NB2*NSP, TKB, 0, stream>>>(p);
  kM<<<NB2, 64, 0, stream>>>(p);
  kR<<<NB2, 64, 0, stream>>>(p);
  kD<<<1, TPB, 0, stream>>>(p);
}

// Round 19
// 151.102 us; speedup vs baseline: 1.5269x; 1.0982x over previous
//
#include <hip/hip_runtime.h>
#include <hip/hip_bf16.h>
#include <stdint.h>

#define BB 32
#define GG 100
#define AA 8400
#define TPB 256
#define NCH 33                         // ceil(8400/256) chunks per image
#define TKB 512                        // kB block size (8 waves)
#define BA (BB*AA)
#define NG (BB*GG)
#define NB2 (BB*GG)                    // kR blocks / partial count
#define NITB 17                        // ceil(AA/TKB) kB screen iterations
#define PCAP 8416                      // positives cap (>= AA, cannot overflow)
#define GCAP 128                       // geo cap (provably <= 75 per gt)
#define SCAP (GG*10)                   // selection slots per image (g*10+k)

typedef __hip_bfloat16 bf16;

struct P {
  const void *outs, *labs, *ss;
  float4 *box4, *gtb, *gtc;           // per-anchor box; per-gt box/center
  float2 *aux2;                       // per-anchor (fg? area : -area, cpk bits)
  float *pcc, *zl;                    // per-anchor cls-cost / cls logit
  int   *sel_a;                       // [BB][SCAP] selected anchor id, -1 empty
  float *sel_iou;                     // [BB][SCAP] its iou
  int   *cnt, *own;                   // per-anchor selection count / min slot
  float *pb, *pf;                     // per-(b,g) BCE / fg partials
  int *gmax;
  float *out;
};

// runtime input-dtype detection: strides[0]==8.0
// f32 word 0x41000000 ; bf16 pair (8.0,8.0) 0x41004100
__device__ __forceinline__ int dtypeFlag(const void* ss){
  return (((const uint32_t*)ss)[0] == 0x41000000u) ? 1 : 0;
}
__device__ __forceinline__ float ld(const void* p, int i, int isf32){
  return isf32 ? ((const float*)p)[i] : __bfloat162float(((const bf16*)p)[i]);
}
// analytic anchor geometry (exact: ints + pow2 strides exact in f32/bf16)
__device__ __forceinline__ void ageom(int a, float& xc, float& yc, float& r){
  int x, y, s;
  if (a < 6400){ x = a % 80; y = a / 80; s = 8; }
  else if (a < 8000){ int q = a - 6400; x = q % 40; y = q / 40; s = 16; }
  else { int q = a - 8000; x = q % 20; y = q / 20; s = 32; }
  float fs = (float)s;
  xc = ((float)x + 0.5f) * fs;
  yc = ((float)y + 0.5f) * fs;
  r  = 2.5f * fs;
}
// pack integer center + level: xc(10) | yc(10)<<10 | lvl<<20
__device__ __forceinline__ uint32_t apack2(int a){
  int x, y, s, lvl;
  if (a < 6400){ x = a % 80; y = a / 80; s = 8; lvl = 0; }
  else if (a < 8000){ int q = a - 6400; x = q % 40; y = q / 40; s = 16; lvl = 1; }
  else { int q = a - 8000; x = q % 20; y = q / 20; s = 32; lvl = 2; }
  return (uint32_t)(x*s + s/2) | ((uint32_t)(y*s + s/2) << 10) | ((uint32_t)lvl << 20);
}

// ---- kA: gt structs + per-anchor staging + fg (identity layout) -----------
// r14 verbatim (best-known 151.6, absmax 0). Session journal: r15 thin-kA
// (pool unchanged -> kA writes never a cost, raw-load kB +7us), r16 prefetch
// (+1us, compiler already covers), r17 anchor-major (121us, 3x less
// parallelism), r18 span-split (55.4us screen; == kB's floor, extra stage
// cost more than saved). Screen floor ~55-57us demonstrated across 4
// decompositions; this is the best-known overall configuration.
__global__ __launch_bounds__(TPB) void kA(P p){
  __shared__ float4 s_gtb[GG], s_gtc[GG];
  __shared__ float s_o[TPB*6];
  __shared__ int s_ng;
  int t = threadIdx.x;
  int c = blockIdx.x, b = blockIdx.y;
  int isf = dtypeFlag(p.ss);
  if (t == 0) s_ng = 0;
  {
    int s = c*TPB + t;
    if (s < SCAP) p.sel_a[b*SCAP + s] = -1;        // empty slot marker
  }
  int nel = min(TPB*6, AA*6 - c*(TPB*6));      // floats in this chunk
  if (isf){
    const float4* src = (const float4*)((const float*)p.outs + (size_t)b*AA*6 + (size_t)c*(TPB*6));
    float4* dst = (float4*)s_o;
    for (int i = t; i < nel/4; i += TPB) dst[i] = src[i];
  } else {
    const uint4* src = (const uint4*)((const bf16*)p.outs + (size_t)b*AA*6 + (size_t)c*(TPB*6));
    for (int i = t; i < nel/8; i += TPB){
      uint4 u = src[i];
      int o = i*8;
      s_o[o+0]=__uint_as_float(u.x<<16); s_o[o+1]=__uint_as_float(u.x&0xffff0000u);
      s_o[o+2]=__uint_as_float(u.y<<16); s_o[o+3]=__uint_as_float(u.y&0xffff0000u);
      s_o[o+4]=__uint_as_float(u.z<<16); s_o[o+5]=__uint_as_float(u.z&0xffff0000u);
      s_o[o+6]=__uint_as_float(u.w<<16); s_o[o+7]=__uint_as_float(u.w&0xffff0000u);
    }
  }
  __syncthreads();
  if (t < GG){
    int i = b*GG + t;
    float l0 = ld(p.labs, i*5  , isf);
    float gcx= ld(p.labs, i*5+1, isf);
    float gcy= ld(p.labs, i*5+2, isf);
    float gw = ld(p.labs, i*5+3, isf);
    float gh = ld(p.labs, i*5+4, isf);
    int valid = (l0+gcx+gcy+gw+gh) > 0.f;
    float4 vb = make_float4(gcx-gw*0.5f, gcy-gh*0.5f, gcx+gw*0.5f, gcy+gh*0.5f);
    float4 vc = make_float4(gcx, gcy, gw*gh, valid ? 1.f : 0.f);
    s_gtb[t] = vb; s_gtc[t] = vc;
    if (c == 0){ p.gtb[i] = vb; p.gtc[i] = vc; }
    if (valid) atomicMax(&s_ng, t+1);
  }
  __syncthreads();
  int ng = s_ng;
  if (c == 0 && t == 0) p.gmax[b] = ng;
  int a = c*TPB + t;
  if (a < AA){
    float cx=s_o[t*6], cy=s_o[t*6+1], w=s_o[t*6+2], h=s_o[t*6+3], ob=s_o[t*6+4], cl=s_o[t*6+5];
    int idx = b*AA + a;
    p.box4[idx] = make_float4(cx-w*0.5f, cy-h*0.5f, cx+w*0.5f, cy+h*0.5f);
    float so = 1.f/(1.f+expf(-ob));
    float sc = 1.f/(1.f+expf(-cl));
    float pccv = -logf(sqrtf(sc*so) + 1e-9f);
    float xc, yc, r; ageom(a, xc, yc, r);
    int fg = 0;
    for (int g = 0; g < ng; ++g){
      float4 gb = s_gtb[g], gc = s_gtc[g];
      bool inb = (xc>gb.x)&&(xc<gb.z)&&(yc>gb.y)&&(yc<gb.w);
      bool inc = (fabsf(xc-gc.x)<r)&&(fabsf(yc-gc.y)<r);
      fg |= (gc.w != 0.f) && (inb||inc);
    }
    float area = w*h;                       // >= 16 (w,h >= 4): sign trick safe
    p.aux2[idx] = make_float2(fg ? area : -area, __uint_as_float(apack2(a)));
    p.pcc[idx] = pccv;
    p.zl [idx] = cl;
    p.cnt[idx] = 0;
    p.own[idx] = 0x7fffffff;
  }
}

// ---- kB: per-(b,g) dyn_k + selection (packed geom; r14 verbatim) ----------
__global__ __launch_bounds__(TKB) void kB(P p){
  __shared__ float s_pos[PCAP];
  __shared__ float s_gcost[GCAP];
  __shared__ int   s_gpos[GCAP];
  __shared__ int   s_pcnt, s_gcnt;
  int t = threadIdx.x;
  int lane = t & 63, wid = t >> 6;
  int item = blockIdx.x;
  int b = item / GG, g = item - b*GG;       // balanced across XCDs
  if (t == 0){ s_pcnt = 0; s_gcnt = 0; }
  float4 gc = p.gtc[b*GG+g];
  if (gc.w == 0.f) return;                  // uniform exit, pre-barrier
  float4 gb = p.gtb[b*GG+g];
  float glx=gb.x, gly=gb.y, ghx=gb.z, ghy=gb.w, gcx=gc.x, gcy=gc.y, ga=gc.z;
  int base = b*AA;
  unsigned long long lmlt = (1ull<<lane) - 1ull;
  __syncthreads();                          // s_pcnt/s_gcnt init visible

  // main screen over all AA anchors; heavy math only on hits
  for (int it = 0; it < NITB; ++it){
    int pos = it*TKB + t;
    bool ovl = false, geo = false;
    float v = 0.f, cst = 0.f;
    if (pos < AA){
      float2 aux = p.aux2[base+pos];
      float4 bx  = p.box4[base+pos];
      bool fg = aux.x > 0.f;
      uint32_t u = __float_as_uint(aux.y);
      float xc = (float)(u & 1023u), yc = (float)((u>>10)&1023u);
      float r  = (float)(20u << (u>>20));
      bool inb = (xc>glx)&&(xc<ghx)&&(yc>gly)&&(yc<ghy);
      geo = inb && (fabsf(xc-gcx)<r) && (fabsf(yc-gcy)<r);   // geo => fg
      float tlx=fmaxf(glx,bx.x), tly=fmaxf(gly,bx.y);
      float brx=fminf(ghx,bx.z), bry=fminf(ghy,bx.w);
      float iw=brx-tlx, ih=bry-tly;
      ovl = fg && (iw>0.f) && (ih>0.f);
      if (ovl | geo){
        float area = fabsf(aux.x);
        float inter = fmaxf(iw,0.f)*fmaxf(ih,0.f);
        v = inter/(ga + area - inter + 1e-12f);
        if (geo) cst = p.pcc[base+pos] + 3.f*(-logf(v+1e-8f));
      }
    }
    unsigned long long m1 = __ballot(ovl);
    if (m1){
      int ldr = (int)(__ffsll(m1)-1);
      int off;
      if (lane == ldr) off = atomicAdd(&s_pcnt, __popcll(m1));
      off = __shfl(off, ldr);
      if (ovl) s_pos[off + __popcll(m1 & lmlt)] = v;
    }
    unsigned long long m2 = __ballot(geo);
    if (m2){
      int ldr = (int)(__ffsll(m2)-1);
      int off;
      if (lane == ldr) off = atomicAdd(&s_gcnt, __popcll(m2));
      off = __shfl(off, ldr);
      if (geo){
        int q = off + __popcll(m2 & lmlt);
        s_gcost[q] = cst; s_gpos[q] = pos;
      }
    }
  }
  __syncthreads();
  if (wid) return;                          // 7 waves released; wave 0 selects

  int pcnt = s_pcnt, gcnt = s_gcnt;         // gcnt <= 75 < GCAP

  // dk: top-10 positives by pop-extraction over s_pos (values only;
  // descending add order == jnp top_k sum order; zeros add exactly 0)
  float lmax = -1.f;
  for (int i = lane; i < pcnt; i += 64) lmax = fmaxf(lmax, s_pos[i]);
  float sum = 0.f;
  for (int k = 0; k < 10; ++k){
    float gv = lmax;
#pragma unroll
    for (int off=32; off; off>>=1) gv = fmaxf(gv, __shfl_xor(gv, off));
    if (gv <= 0.f) break;
    sum += gv;
    unsigned long long ms = __ballot(lmax == gv);
    if ((int)(__ffsll(ms)-1) == lane){      // unique owner: remove 1 instance
      bool fnd = false; float nl = -1.f;
      for (int i = lane; i < pcnt; i += 64){
        float vv = s_pos[i];
        if (!fnd && vv == gv){ fnd = true; vv = -1.f; s_pos[i] = vv; }
        nl = fmaxf(nl, vv);
      }
      lmax = nl;
    }
  }
  int dk = (int)sum; if (dk<1) dk=1; if (dk>10) dk=10;

  // selection among geo (<=2 entries/lane; all geo < all non-geo cost)
  float c0=3.0e38f, c1=3.0e38f; int p0=0x7fffffff, p1=0x7fffffff;
  if (lane < gcnt){ c0 = s_gcost[lane]; p0 = s_gpos[lane]; }
  if (lane+64 < gcnt){ c1 = s_gcost[lane+64]; p1 = s_gpos[lane+64]; }
  if (c1 < c0 || (c1==c0 && p1<p0)){
    float tc=c0; c0=c1; c1=tc; int tp=p0; p0=p1; p1=tp;
  }
  int mysel = -1, take = 0;
  for (int k = 0; k < dk; ++k){
    float gv=c0; int gi=p0;
#pragma unroll
    for (int off=32; off; off>>=1){
      float ov=__shfl_xor(gv,off); int oi=__shfl_xor(gi,off);
      if (ov<gv || (ov==gv && oi<gi)){ gv=ov; gi=oi; }
    }
    if (gv >= 2.9e38f) break;               // geo exhausted
    if (lane == k) mysel = gi;
    take++;
    if (c0==gv && p0==gi){ c0=c1; p0=p1; c1=3.0e38f; p1=0x7fffffff; }
  }

  // rare fallback: need (dk-take) non-geo picks; exact k-th smallest via
  // repeated rescan excluding previous picks by strict lex >
  float lastc = -3.0e38f; int lastp = -1;
  for (int k = take; k < dk; ++k){
    float bc = 3.0e38f; int bp = 0x7fffffff;
    int n64 = (AA + 63) >> 6;
    for (int it = 0; it < n64; ++it){
      int pos = (it<<6) + lane;
      if (pos < AA){
        float2 aux = p.aux2[base+pos];
        bool fg = aux.x > 0.f;
        if (fg){
          uint32_t u = __float_as_uint(aux.y);
          float xc = (float)(u & 1023u), yc = (float)((u>>10)&1023u);
          float r  = (float)(20u << (u>>20));
          bool inb = (xc>glx)&&(xc<ghx)&&(yc>gly)&&(yc<ghy);
          bool geo2 = inb && (fabsf(xc-gcx)<r) && (fabsf(yc-gcy)<r);
          if (!geo2){
            float4 bx = p.box4[base+pos];
            float tlx=fmaxf(glx,bx.x), tly=fmaxf(gly,bx.y);
            float brx=fminf(ghx,bx.z), bry=fminf(ghy,bx.w);
            float iw=fmaxf(brx-tlx,0.f), ih=fmaxf(bry-tly,0.f);
            float inter=iw*ih;
            float area = fabsf(aux.x);
            float v = inter/(ga + area - inter + 1e-12f);
            float cst = p.pcc[base+pos] + 3.f*(-logf(v+1e-8f)) + 100000.f;
            bool gt = (cst > lastc) || (cst == lastc && pos > lastp);
            bool lt = (cst < bc)   || (cst == bc   && pos < bp);
            if (gt && lt){ bc = cst; bp = pos; }
          }
        }
      }
    }
#pragma unroll
    for (int off=32; off; off>>=1){
      float ov=__shfl_xor(bc,off); int oi=__shfl_xor(bp,off);
      if (ov<bc || (ov==bc && oi<bp)){ bc=ov; bp=oi; }
    }
    if (bc >= 2.9e38f) break;               // candidates exhausted
    if (lane == k) mysel = bp;
    lastc = bc; lastp = bp;
  }

  if (mysel >= 0){                          // lanes 0..dk-1 hold selections
    int a = mysel;                          // pos == anchor id
    float4 bx = p.box4[base+a];
    float area = fabsf(p.aux2[base+a].x);
    float tlx=fmaxf(glx,bx.x), tly=fmaxf(gly,bx.y);
    float brx=fminf(ghx,bx.z), bry=fminf(ghy,bx.w);
    float iw=fmaxf(brx-tlx,0.f), ih=fmaxf(bry-tly,0.f);
    float inter=iw*ih;
    float iou=inter/(ga + area - inter + 1e-12f);
    int slot = g*10 + lane;                 // deterministic slot id
    p.sel_a [b*SCAP + slot] = a;
    p.sel_iou[b*SCAP + slot] = iou;
    atomicAdd(&p.cnt[base+a], 1);
    atomicMin(&p.own[base+a], slot);        // commutative -> deterministic owner
  }
}

// ---- kR: per-(b,g) resolution + BCE partials (r14 verbatim) ---------------
__global__ __launch_bounds__(64) void kR(P p){
  int lane = threadIdx.x;
  int item = blockIdx.x;
  int b = item / GG, g = item - b*GG;
  int base = b*AA;
  int a = -1, cgt = 0;
  bool ownr = false;
  float iouv = 0.f;
  if (lane < 10){
    int slot = g*10 + lane;
    a = p.sel_a[b*SCAP + slot];
    if (a >= 0 && p.own[base+a] == slot){
      ownr = true;
      cgt = p.cnt[base+a];
      iouv = p.sel_iou[b*SCAP + slot];      // final value when cgt==1
    }
  }
  unsigned long long cm = __ballot(ownr && cgt > 1);
  if (cm){
    int ng = p.gmax[b];
    while (cm){
      int s = (int)(__ffsll(cm)-1); cm &= cm - 1ull;
      int aa = __shfl(a, s);
      float area = fabsf(p.aux2[base+aa].x);
      float pccv = p.pcc[base+aa];
      float4 bx = p.box4[base+aa];
      float xc,yc,r; ageom(aa,xc,yc,r);
      float bc = 3.9e38f, bi = 0.f; int bg = 0x7fffffff;
      for (int g2 = lane; g2 < ng; g2 += 64){
        float4 gbb = p.gtb[b*GG+g2], gcc = p.gtc[b*GG+g2];
        float cost, iou2 = 0.f;
        if (gcc.w != 0.f){
          float tlx=fmaxf(gbb.x,bx.x), tly=fmaxf(gbb.y,bx.y);
          float brx=fminf(gbb.z,bx.z), bry=fminf(gbb.w,bx.w);
          float iw=fmaxf(brx-tlx,0.f), ih=fmaxf(bry-tly,0.f);
          float inter=iw*ih;
          iou2 = inter/(gcc.z + area - inter + 1e-12f);
          bool inb=(xc>gbb.x)&&(xc<gbb.z)&&(yc>gbb.y)&&(yc<gbb.w);
          bool inc=(fabsf(xc-gcc.x)<r)&&(fabsf(yc-gcc.y)<r);
          cost = pccv + 3.f*(-logf(iou2+1e-8f)) + ((inb&&inc)?0.f:100000.f);
        } else cost = 1e9f;
        if (cost < bc){ bc=cost; bi=iou2; bg=g2; }   // lane-local first-min
      }
#pragma unroll
      for (int off=32; off; off>>=1){
        float oc=__shfl_xor(bc,off), oi=__shfl_xor(bi,off);
        int og=__shfl_xor(bg,off);
        if (oc<bc || (oc==bc && og<bg)){ bc=oc; bi=oi; bg=og; }
      }
      if (lane == s) iouv = bi;             // deliver to owning lane
    }
  }
  float bce = 0.f, fgv = 0.f;
  if (lane < 10 && ownr){
    float z = p.zl[base+a];
    float e = expf(-fabsf(z));
    float spz = fmaxf(z,0.f)+log1pf(e);
    float spn = fmaxf(-z,0.f)+log1pf(e);
    bce = iouv*spn + (1.f-iouv)*spz;
    fgv = 1.f;
  }
#pragma unroll
  for (int off=32; off; off>>=1){
    bce += __shfl_xor(bce, off);
    fgv += __shfl_xor(fgv, off);
  }
  if (lane == 0){ p.pb[item] = bce; p.pf[item] = fgv; }
}

// ---- kD: reduce 3200 partials + finalize (1 block) -------------------------
__global__ __launch_bounds__(TPB) void kD(P p){
  int t = threadIdx.x;
  float sb=0.f, sf=0.f;
  for (int i = t; i < NB2; i += TPB){ sb += p.pb[i]; sf += p.pf[i]; }
#pragma unroll
  for (int off=32; off; off>>=1){
    sb += __shfl_xor(sb, off);
    sf += __shfl_xor(sf, off);
  }
  __shared__ float s_b[4], s_f[4];
  int lane = t & 63, wid = t >> 6;
  if (lane==0){ s_b[wid]=sb; s_f[wid]=sf; }
  __syncthreads();
  if (t==0){
    float tb=s_b[0]+s_b[1]+s_b[2]+s_b[3];
    float tf=s_f[0]+s_f[1]+s_f[2]+s_f[3];
    p.out[0] = tb / fmaxf(tf, 1.f);
  }
}

extern "C" void kernel_launch(void* const* d_in, const int* in_sizes, int n_in,
                              void* d_out, int out_size, void* d_ws, size_t ws_size,
                              hipStream_t stream) {
  P p;
  p.outs = d_in[0];
  p.labs = d_in[1];
  p.ss   = d_in[4];
  char* w = (char*)d_ws;
  p.box4  = (float4*)w; w += (size_t)BA*sizeof(float4);
  p.gtb   = (float4*)w; w += (size_t)NG*sizeof(float4);
  p.gtc   = (float4*)w; w += (size_t)NG*sizeof(float4);
  p.aux2  = (float2*)w; w += (size_t)BA*sizeof(float2);
  p.pcc   = (float*)w;  w += (size_t)BA*sizeof(float);
  p.zl    = (float*)w;  w += (size_t)BA*sizeof(float);
  p.sel_a = (int*)w;    w += (size_t)BB*SCAP*sizeof(int);
  p.sel_iou=(float*)w;  w += (size_t)BB*SCAP*sizeof(float);
  p.cnt   = (int*)w;    w += (size_t)BA*sizeof(int);
  p.own   = (int*)w;    w += (size_t)BA*sizeof(int);
  p.gmax  = (int*)w;    w += (size_t)BB*sizeof(int);
  p.pb    = (float*)w;  w += (size_t)NB2*sizeof(float);
  p.pf    = (float*)w;  w += (size_t)NB2*sizeof(float);
  p.out   = (float*)d_out;

  kA<<<dim3(NCH, BB), TPB, 0, stream>>>(p);
  kB<<<BB*GG, TKB, 0, stream>>>(p);
  kR<<<NB2, 64, 0, stream>>>(p);
  kD<<<1, TPB, 0, stream>>>(p);
}

// Round 20
// 148.618 us; speedup vs baseline: 1.5524x; 1.0167x over previous
//
#include <hip/hip_runtime.h>
#include <hip/hip_bf16.h>
#include <stdint.h>

#define BB 32
#define GG 100
#define AA 8400
#define TPB 256
#define NCH 33                         // ceil(8400/256) chunks per image
#define TKB 512                        // kB2 block size (8 waves)
#define BA (BB*AA)
#define NG (BB*GG)
#define NB2 (BB*GG)                    // kB2/kR blocks
#define NCX 10                         // 10x10 grid of 64px cells
#define NCELL 100
#define PCAP 8416                      // positives cap (>= AA)
#define GCAP 128                       // geo cap (provably <= 75 per gt)
#define SCAP (GG*10)                   // selection slots per image

typedef __hip_bfloat16 bf16;

struct P {
  const void *outs, *labs, *ss;
  float4 *box4, *gtb, *gtc;           // per-anchor box; per-gt box/center
  float2 *aux2;                       // per-anchor (fg? area : -area, cpk bits)
  float *pcc, *zl;                    // per-anchor cls-cost / cls logit
  int   *cellid;                      // per-anchor pred-center cell
  int   *chunkcell;                   // [BB][NCH][NCELL] per-chunk cell counts
  int   *bstart, *btot;               // [BB][NCELL] cell start / count
  float *barea;                       // binned fg-signed area
  float4 *bb4;                        // binned pred box
  int   *sel_a;                       // [BB][SCAP] selected anchor id, -1 empty
  float *sel_iou;                     // [BB][SCAP] its iou
  int   *cnt, *own;                   // per-anchor selection count / min slot
  float *pb, *pf;                     // per-(b,g) BCE / fg partials
  int *gmax;
  float *out;
};

__device__ __forceinline__ int dtypeFlag(const void* ss){
  return (((const uint32_t*)ss)[0] == 0x41000000u) ? 1 : 0;
}
__device__ __forceinline__ float ld(const void* p, int i, int isf32){
  return isf32 ? ((const float*)p)[i] : __bfloat162float(((const bf16*)p)[i]);
}
__device__ __forceinline__ void ageom(int a, float& xc, float& yc, float& r){
  int x, y, s;
  if (a < 6400){ x = a % 80; y = a / 80; s = 8; }
  else if (a < 8000){ int q = a - 6400; x = q % 40; y = q / 40; s = 16; }
  else { int q = a - 8000; x = q % 20; y = q / 20; s = 32; }
  float fs = (float)s;
  xc = ((float)x + 0.5f) * fs;
  yc = ((float)y + 0.5f) * fs;
  r  = 2.5f * fs;
}
__device__ __forceinline__ uint32_t apack2(int a){
  int x, y, s, lvl;
  if (a < 6400){ x = a % 80; y = a / 80; s = 8; lvl = 0; }
  else if (a < 8000){ int q = a - 6400; x = q % 40; y = q / 40; s = 16; lvl = 1; }
  else { int q = a - 8000; x = q % 20; y = q / 20; s = 32; lvl = 2; }
  return (uint32_t)(x*s + s/2) | ((uint32_t)(y*s + s/2) << 10) | ((uint32_t)lvl << 20);
}

// ---- kA: r14 verbatim + pred-center cell histogram (cellid + chunkcell) ---
__global__ __launch_bounds__(TPB) void kA(P p){
  __shared__ float4 s_gtb[GG], s_gtc[GG];
  __shared__ float s_o[TPB*6];
  __shared__ int s_ng;
  __shared__ int s_h[NCELL];
  int t = threadIdx.x;
  int c = blockIdx.x, b = blockIdx.y;
  int isf = dtypeFlag(p.ss);
  if (t == 0) s_ng = 0;
  if (t < NCELL) s_h[t] = 0;
  {
    int s = c*TPB + t;
    if (s < SCAP) p.sel_a[b*SCAP + s] = -1;        // empty slot marker
  }
  int nel = min(TPB*6, AA*6 - c*(TPB*6));
  if (isf){
    const float4* src = (const float4*)((const float*)p.outs + (size_t)b*AA*6 + (size_t)c*(TPB*6));
    float4* dst = (float4*)s_o;
    for (int i = t; i < nel/4; i += TPB) dst[i] = src[i];
  } else {
    const uint4* src = (const uint4*)((const bf16*)p.outs + (size_t)b*AA*6 + (size_t)c*(TPB*6));
    for (int i = t; i < nel/8; i += TPB){
      uint4 u = src[i];
      int o = i*8;
      s_o[o+0]=__uint_as_float(u.x<<16); s_o[o+1]=__uint_as_float(u.x&0xffff0000u);
      s_o[o+2]=__uint_as_float(u.y<<16); s_o[o+3]=__uint_as_float(u.y&0xffff0000u);
      s_o[o+4]=__uint_as_float(u.z<<16); s_o[o+5]=__uint_as_float(u.z&0xffff0000u);
      s_o[o+6]=__uint_as_float(u.w<<16); s_o[o+7]=__uint_as_float(u.w&0xffff0000u);
    }
  }
  __syncthreads();
  if (t < GG){
    int i = b*GG + t;
    float l0 = ld(p.labs, i*5  , isf);
    float gcx= ld(p.labs, i*5+1, isf);
    float gcy= ld(p.labs, i*5+2, isf);
    float gw = ld(p.labs, i*5+3, isf);
    float gh = ld(p.labs, i*5+4, isf);
    int valid = (l0+gcx+gcy+gw+gh) > 0.f;
    float4 vb = make_float4(gcx-gw*0.5f, gcy-gh*0.5f, gcx+gw*0.5f, gcy+gh*0.5f);
    float4 vc = make_float4(gcx, gcy, gw*gh, valid ? 1.f : 0.f);
    s_gtb[t] = vb; s_gtc[t] = vc;
    if (c == 0){ p.gtb[i] = vb; p.gtc[i] = vc; }
    if (valid) atomicMax(&s_ng, t+1);
  }
  __syncthreads();
  int ng = s_ng;
  if (c == 0 && t == 0) p.gmax[b] = ng;
  int a = c*TPB + t;
  if (a < AA){
    float cx=s_o[t*6], cy=s_o[t*6+1], w=s_o[t*6+2], h=s_o[t*6+3], ob=s_o[t*6+4], cl=s_o[t*6+5];
    int idx = b*AA + a;
    p.box4[idx] = make_float4(cx-w*0.5f, cy-h*0.5f, cx+w*0.5f, cy+h*0.5f);
    float so = 1.f/(1.f+expf(-ob));
    float sc = 1.f/(1.f+expf(-cl));
    float pccv = -logf(sqrtf(sc*so) + 1e-9f);
    float xc, yc, r; ageom(a, xc, yc, r);
    int fg = 0;
    for (int g = 0; g < ng; ++g){
      float4 gb = s_gtb[g], gc = s_gtc[g];
      bool inb = (xc>gb.x)&&(xc<gb.z)&&(yc>gb.y)&&(yc<gb.w);
      bool inc = (fabsf(xc-gc.x)<r)&&(fabsf(yc-gc.y)<r);
      fg |= (gc.w != 0.f) && (inb||inc);
    }
    float area = w*h;                       // >= 16: sign trick safe
    p.aux2[idx] = make_float2(fg ? area : -area, __uint_as_float(apack2(a)));
    p.pcc[idx] = pccv;
    p.zl [idx] = cl;
    p.cnt[idx] = 0;
    p.own[idx] = 0x7fffffff;
    int cxi = min(NCX-1, (int)(cx * 0.015625f));   // cx >= 0
    int cyi = min(NCX-1, (int)(cy * 0.015625f));
    int cell = cyi*NCX + cxi;
    p.cellid[idx] = cell;
    atomicAdd(&s_h[cell], 1);
  }
  __syncthreads();
  if (t < NCELL) p.chunkcell[(b*NCH + c)*NCELL + t] = s_h[t];
}

// ---- kY: deterministic-range binned scatter (kE-style, no global cursors) -
// Each block recomputes the image cell prefix from chunkcell (complete after
// kA) + its own chunk offset -> LDS cursors. Order within a cell is
// irrelevant: positives are a value multiset; geo/selection use original ids.
__global__ __launch_bounds__(TPB) void kY(P p){
  __shared__ int s_cnt[NCELL], s_pre[NCELL], s_cur[NCELL], s_sta[NCELL];
  int t = threadIdx.x, c = blockIdx.x, b = blockIdx.y;
  if (t < NCELL){
    int tot = 0, pre = 0;
    for (int k = 0; k < NCH; ++k){
      int v = p.chunkcell[(b*NCH + k)*NCELL + t];
      tot += v;
      if (k < c) pre += v;
    }
    s_cnt[t] = tot; s_pre[t] = pre;
  }
  __syncthreads();
  if (t == 0){
    int run = 0;
    for (int j = 0; j < NCELL; ++j){
      s_sta[j] = run;
      s_cur[j] = run + s_pre[j];
      run += s_cnt[j];
    }
  }
  __syncthreads();
  if (c == 0 && t < NCELL){
    p.bstart[b*NCELL + t] = s_sta[t];
    p.btot  [b*NCELL + t] = s_cnt[t];
  }
  int a = c*TPB + t;
  if (a < AA){
    int idx = b*AA + a;
    int cell = p.cellid[idx];
    int q = atomicAdd(&s_cur[cell], 1);     // disjoint [sta+pre, sta+pre+cnt)
    p.barea[b*AA + q] = p.aux2[idx].x;
    p.bb4  [b*AA + q] = p.box4[idx];
  }
}

// ---- kB2: binned screen + analytic geo + r14 selection --------------------
// Screen only cells intersecting gt box +-64 (overlap => pred center there;
// conservative trunc-monotone ranges, exact tests inside -> positives
// multiset identical to r14, bit-exact dk). Geo enumerated analytically per
// level (<=75; integer anchor centers bit-exact; expressions verbatim).
__global__ __launch_bounds__(TKB) void kB2(P p){
  __shared__ float s_pos[PCAP];
  __shared__ float s_gcost[GCAP];
  __shared__ int   s_gpos[GCAP];
  __shared__ int   s_pcnt;
  int t = threadIdx.x;
  int lane = t & 63, wid = t >> 6;
  int item = blockIdx.x;
  int b = item / GG, g = item - b*GG;
  if (t == 0) s_pcnt = 0;
  float4 gc = p.gtc[item];
  if (gc.w == 0.f) return;                  // uniform, pre-barrier
  float4 gb = p.gtb[item];
  float glx=gb.x, gly=gb.y, ghx=gb.z, ghy=gb.w, gcx=gc.x, gcy=gc.y, ga=gc.z;
  int base = b*AA;
  unsigned long long lmlt = (1ull<<lane) - 1ull;
  __syncthreads();

  int c0x = max(0, (int)((glx - 64.f) * 0.015625f));
  int c1x = min(NCX-1, (int)((ghx + 64.f) * 0.015625f));
  int c0y = max(0, (int)((gly - 64.f) * 0.015625f));
  int c1y = min(NCX-1, (int)((ghy + 64.f) * 0.015625f));

  for (int cy = c0y; cy <= c1y; ++cy){      // rows: contiguous binned spans
    int cl0 = cy*NCX + c0x, cl1 = cy*NCX + c1x;
    int s0 = p.bstart[b*NCELL + cl0];
    int s1 = p.bstart[b*NCELL + cl1] + p.btot[b*NCELL + cl1];
    int nit = (s1 - s0 + TKB - 1) / TKB;    // uniform
    for (int it = 0; it < nit; ++it){
      int i = s0 + it*TKB + t;
      bool ovl = false; float v = 0.f;
      if (i < s1){
        float ar = p.barea[base + i];
        if (ar > 0.f){                      // fg
          float4 bx = p.bb4[base + i];
          float tlx=fmaxf(glx,bx.x), tly=fmaxf(gly,bx.y);
          float brx=fminf(ghx,bx.z), bry=fminf(ghy,bx.w);
          float iw=brx-tlx, ih=bry-tly;
          ovl = (iw>0.f) && (ih>0.f);
          if (ovl){
            float inter = fmaxf(iw,0.f)*fmaxf(ih,0.f);
            v = inter/(ga + ar - inter + 1e-12f);
          }
        }
      }
      unsigned long long m1 = __ballot(ovl);
      if (m1){
        int ldr = (int)(__ffsll(m1)-1);
        int off;
        if (lane == ldr) off = atomicAdd(&s_pcnt, __popcll(m1));
        off = __shfl(off, ldr);
        if (ovl) s_pos[off + __popcll(m1 & lmlt)] = v;
      }
    }
  }
  __syncthreads();
  if (wid) return;                          // 7 waves released; wave 0 finishes

  // analytic geo enumeration (wave 0; exact gates; same-wave LDS, no barrier)
  int gcnt = 0, lbase = 0;
  for (int lvl = 0; lvl < 3; ++lvl){
    int s = 8 << lvl, n = 80 >> lvl;
    float fr = (float)(20 << lvl);
    float hs = 0.5f * (float)s;
    float lox = fmaxf(glx, gcx - fr), hix = fminf(ghx, gcx + fr);
    float loy = fmaxf(gly, gcy - fr), hiy = fminf(ghy, gcy + fr);
    int x0 = max(0, (int)((lox - hs) / (float)s));
    int x1 = min(n-1, (int)((hix - hs) / (float)s) + 1);
    int y0 = max(0, (int)((loy - hs) / (float)s));
    int y1 = min(n-1, (int)((hiy - hs) / (float)s) + 1);
    int W = x1 - x0 + 1, H = y1 - y0 + 1;
    if (W > 0 && H > 0){
      int N = W * H;
      int nit2 = (N + 63) >> 6;
      for (int it2 = 0; it2 < nit2; ++it2){
        int i2 = it2*64 + lane;
        bool geo = false; float cst = 0.f; int aid = 0;
        if (i2 < N){
          int xx = x0 + i2 % W, yy = y0 + i2 / W;
          float xc = (float)(xx*s + (s>>1));
          float yc = (float)(yy*s + (s>>1));
          bool inb = (xc>glx)&&(xc<ghx)&&(yc>gly)&&(yc<ghy);
          geo = inb && (fabsf(xc-gcx)<fr) && (fabsf(yc-gcy)<fr);
          if (geo){
            aid = lbase + yy*n + xx;
            float area = fabsf(p.aux2[base+aid].x);
            float4 bx = p.box4[base+aid];
            float tlx=fmaxf(glx,bx.x), tly=fmaxf(gly,bx.y);
            float brx=fminf(ghx,bx.z), bry=fminf(ghy,bx.w);
            float iw=brx-tlx, ih=bry-tly;
            float inter = fmaxf(iw,0.f)*fmaxf(ih,0.f);
            float v = inter/(ga + area - inter + 1e-12f);
            cst = p.pcc[base+aid] + 3.f*(-logf(v+1e-8f));
          }
        }
        unsigned long long m2 = __ballot(geo);
        if (geo){
          int q = gcnt + __popcll(m2 & lmlt);
          s_gcost[q] = cst; s_gpos[q] = aid;
        }
        gcnt += __popcll(m2);
      }
    }
    lbase += n*n;
  }

  int pcnt = s_pcnt;                        // gcnt <= 75 < GCAP

  // dk: top-10 positives by pop-extraction (r14 verbatim)
  float lmax = -1.f;
  for (int i = lane; i < pcnt; i += 64) lmax = fmaxf(lmax, s_pos[i]);
  float sum = 0.f;
  for (int k = 0; k < 10; ++k){
    float gv = lmax;
#pragma unroll
    for (int off=32; off; off>>=1) gv = fmaxf(gv, __shfl_xor(gv, off));
    if (gv <= 0.f) break;
    sum += gv;
    unsigned long long ms = __ballot(lmax == gv);
    if ((int)(__ffsll(ms)-1) == lane){
      bool fnd = false; float nl = -1.f;
      for (int i = lane; i < pcnt; i += 64){
        float vv = s_pos[i];
        if (!fnd && vv == gv){ fnd = true; vv = -1.f; s_pos[i] = vv; }
        nl = fmaxf(nl, vv);
      }
      lmax = nl;
    }
  }
  int dk = (int)sum; if (dk<1) dk=1; if (dk>10) dk=10;

  // selection among geo (r14 verbatim; (cost,id) lex, order-invariant)
  float c0=3.0e38f, c1=3.0e38f; int p0=0x7fffffff, p1=0x7fffffff;
  if (lane < gcnt){ c0 = s_gcost[lane]; p0 = s_gpos[lane]; }
  if (lane+64 < gcnt){ c1 = s_gcost[lane+64]; p1 = s_gpos[lane+64]; }
  if (c1 < c0 || (c1==c0 && p1<p0)){
    float tc=c0; c0=c1; c1=tc; int tp=p0; p0=p1; p1=tp;
  }
  int mysel = -1, take = 0;
  for (int k = 0; k < dk; ++k){
    float gv=c0; int gi=p0;
#pragma unroll
    for (int off=32; off; off>>=1){
      float ov=__shfl_xor(gv,off); int oi=__shfl_xor(gi,off);
      if (ov<gv || (ov==gv && oi<gi)){ gv=ov; gi=oi; }
    }
    if (gv >= 2.9e38f) break;
    if (lane == k) mysel = gi;
    take++;
    if (c0==gv && p0==gi){ c0=c1; p0=p1; c1=3.0e38f; p1=0x7fffffff; }
  }

  // rare fallback: non-geo picks via exact k-th smallest rescan (r14 verbatim)
  float lastc = -3.0e38f; int lastp = -1;
  for (int k = take; k < dk; ++k){
    float bc = 3.0e38f; int bp = 0x7fffffff;
    int n64 = (AA + 63) >> 6;
    for (int it = 0; it < n64; ++it){
      int pos = (it<<6) + lane;
      if (pos < AA){
        float2 aux = p.aux2[base+pos];
        bool fg = aux.x > 0.f;
        if (fg){
          uint32_t u = __float_as_uint(aux.y);
          float xc = (float)(u & 1023u), yc = (float)((u>>10)&1023u);
          float r  = (float)(20u << (u>>20));
          bool inb = (xc>glx)&&(xc<ghx)&&(yc>gly)&&(yc<ghy);
          bool geo2 = inb && (fabsf(xc-gcx)<r) && (fabsf(yc-gcy)<r);
          if (!geo2){
            float4 bx = p.box4[base+pos];
            float tlx=fmaxf(glx,bx.x), tly=fmaxf(gly,bx.y);
            float brx=fminf(ghx,bx.z), bry=fminf(ghy,bx.w);
            float iw=fmaxf(brx-tlx,0.f), ih=fmaxf(bry-tly,0.f);
            float inter=iw*ih;
            float area = fabsf(aux.x);
            float v = inter/(ga + area - inter + 1e-12f);
            float cst = p.pcc[base+pos] + 3.f*(-logf(v+1e-8f)) + 100000.f;
            bool gt = (cst > lastc) || (cst == lastc && pos > lastp);
            bool lt = (cst < bc)   || (cst == bc   && pos < bp);
            if (gt && lt){ bc = cst; bp = pos; }
          }
        }
      }
    }
#pragma unroll
    for (int off=32; off; off>>=1){
      float ov=__shfl_xor(bc,off); int oi=__shfl_xor(bp,off);
      if (ov<bc || (ov==bc && oi<bp)){ bc=ov; bp=oi; }
    }
    if (bc >= 2.9e38f) break;
    if (lane == k) mysel = bp;
    lastc = bc; lastp = bp;
  }

  if (mysel >= 0){
    int a = mysel;
    float4 bx = p.box4[base+a];
    float area = fabsf(p.aux2[base+a].x);
    float tlx=fmaxf(glx,bx.x), tly=fmaxf(gly,bx.y);
    float brx=fminf(ghx,bx.z), bry=fminf(ghy,bx.w);
    float iw=fmaxf(brx-tlx,0.f), ih=fmaxf(bry-tly,0.f);
    float inter=iw*ih;
    float iou=inter/(ga + area - inter + 1e-12f);
    int slot = g*10 + lane;
    p.sel_a [b*SCAP + slot] = a;
    p.sel_iou[b*SCAP + slot] = iou;
    atomicAdd(&p.cnt[base+a], 1);
    atomicMin(&p.own[base+a], slot);
  }
}

// ---- kR: per-(b,g) resolution + BCE partials (r14 verbatim) ---------------
__global__ __launch_bounds__(64) void kR(P p){
  int lane = threadIdx.x;
  int item = blockIdx.x;
  int b = item / GG, g = item - b*GG;
  int base = b*AA;
  int a = -1, cgt = 0;
  bool ownr = false;
  float iouv = 0.f;
  if (lane < 10){
    int slot = g*10 + lane;
    a = p.sel_a[b*SCAP + slot];
    if (a >= 0 && p.own[base+a] == slot){
      ownr = true;
      cgt = p.cnt[base+a];
      iouv = p.sel_iou[b*SCAP + slot];
    }
  }
  unsigned long long cm = __ballot(ownr && cgt > 1);
  if (cm){
    int ng = p.gmax[b];
    while (cm){
      int s = (int)(__ffsll(cm)-1); cm &= cm - 1ull;
      int aa = __shfl(a, s);
      float area = fabsf(p.aux2[base+aa].x);
      float pccv = p.pcc[base+aa];
      float4 bx = p.box4[base+aa];
      float xc,yc,r; ageom(aa,xc,yc,r);
      float bc = 3.9e38f, bi = 0.f; int bg = 0x7fffffff;
      for (int g2 = lane; g2 < ng; g2 += 64){
        float4 gbb = p.gtb[b*GG+g2], gcc = p.gtc[b*GG+g2];
        float cost, iou2 = 0.f;
        if (gcc.w != 0.f){
          float tlx=fmaxf(gbb.x,bx.x), tly=fmaxf(gbb.y,bx.y);
          float brx=fminf(gbb.z,bx.z), bry=fminf(gbb.w,bx.w);
          float iw=fmaxf(brx-tlx,0.f), ih=fmaxf(bry-tly,0.f);
          float inter=iw*ih;
          iou2 = inter/(gcc.z + area - inter + 1e-12f);
          bool inb=(xc>gbb.x)&&(xc<gbb.z)&&(yc>gbb.y)&&(yc<gbb.w);
          bool inc=(fabsf(xc-gcc.x)<r)&&(fabsf(yc-gcc.y)<r);
          cost = pccv + 3.f*(-logf(iou2+1e-8f)) + ((inb&&inc)?0.f:100000.f);
        } else cost = 1e9f;
        if (cost < bc){ bc=cost; bi=iou2; bg=g2; }
      }
#pragma unroll
      for (int off=32; off; off>>=1){
        float oc=__shfl_xor(bc,off), oi=__shfl_xor(bi,off);
        int og=__shfl_xor(bg,off);
        if (oc<bc || (oc==bc && og<bg)){ bc=oc; bi=oi; bg=og; }
      }
      if (lane == s) iouv = bi;
    }
  }
  float bce = 0.f, fgv = 0.f;
  if (lane < 10 && ownr){
    float z = p.zl[base+a];
    float e = expf(-fabsf(z));
    float spz = fmaxf(z,0.f)+log1pf(e);
    float spn = fmaxf(-z,0.f)+log1pf(e);
    bce = iouv*spn + (1.f-iouv)*spz;
    fgv = 1.f;
  }
#pragma unroll
  for (int off=32; off; off>>=1){
    bce += __shfl_xor(bce, off);
    fgv += __shfl_xor(fgv, off);
  }
  if (lane == 0){ p.pb[item] = bce; p.pf[item] = fgv; }
}

// ---- kD: reduce 3200 partials + finalize (1 block) -------------------------
__global__ __launch_bounds__(TPB) void kD(P p){
  int t = threadIdx.x;
  float sb=0.f, sf=0.f;
  for (int i = t; i < NB2; i += TPB){ sb += p.pb[i]; sf += p.pf[i]; }
#pragma unroll
  for (int off=32; off; off>>=1){
    sb += __shfl_xor(sb, off);
    sf += __shfl_xor(sf, off);
  }
  __shared__ float s_b[4], s_f[4];
  int lane = t & 63, wid = t >> 6;
  if (lane==0){ s_b[wid]=sb; s_f[wid]=sf; }
  __syncthreads();
  if (t==0){
    float tb=s_b[0]+s_b[1]+s_b[2]+s_b[3];
    float tf=s_f[0]+s_f[1]+s_f[2]+s_f[3];
    p.out[0] = tb / fmaxf(tf, 1.f);
  }
}

extern "C" void kernel_launch(void* const* d_in, const int* in_sizes, int n_in,
                              void* d_out, int out_size, void* d_ws, size_t ws_size,
                              hipStream_t stream) {
  P p;
  p.outs = d_in[0];
  p.labs = d_in[1];
  p.ss   = d_in[4];
  char* w = (char*)d_ws;
  p.box4  = (float4*)w; w += (size_t)BA*sizeof(float4);
  p.gtb   = (float4*)w; w += (size_t)NG*sizeof(float4);
  p.gtc   = (float4*)w; w += (size_t)NG*sizeof(float4);
  p.bb4   = (float4*)w; w += (size_t)BA*sizeof(float4);
  p.aux2  = (float2*)w; w += (size_t)BA*sizeof(float2);
  p.pcc   = (float*)w;  w += (size_t)BA*sizeof(float);
  p.zl    = (float*)w;  w += (size_t)BA*sizeof(float);
  p.barea = (float*)w;  w += (size_t)BA*sizeof(float);
  p.cellid= (int*)w;    w += (size_t)BA*sizeof(int);
  p.chunkcell=(int*)w;  w += (size_t)BB*NCH*NCELL*sizeof(int);
  p.bstart= (int*)w;    w += (size_t)BB*NCELL*sizeof(int);
  p.btot  = (int*)w;    w += (size_t)BB*NCELL*sizeof(int);
  p.sel_a = (int*)w;    w += (size_t)BB*SCAP*sizeof(int);
  p.sel_iou=(float*)w;  w += (size_t)BB*SCAP*sizeof(float);
  p.cnt   = (int*)w;    w += (size_t)BA*sizeof(int);
  p.own   = (int*)w;    w += (size_t)BA*sizeof(int);
  p.gmax  = (int*)w;    w += (size_t)BB*sizeof(int);
  p.pb    = (float*)w;  w += (size_t)NB2*sizeof(float);
  p.pf    = (float*)w;  w += (size_t)NB2*sizeof(float);
  p.out   = (float*)d_out;

  kA<<<dim3(NCH, BB), TPB, 0, stream>>>(p);
  kY<<<dim3(NCH, BB), TPB, 0, stream>>>(p);
  kB2<<<NB2, TKB, 0, stream>>>(p);
  kR<<<NB2, 64, 0, stream>>>(p);
  kD<<<1, TPB, 0, stream>>>(p);
}